// Round 13
// baseline (60.086 us; speedup 1.0000x reference)
//
#include <hip/hip_runtime.h>
#include <math.h>

// PseudoGroupContrast — bulk-glds staging, latency-proof streaming design.
//
//   prep:   queue fp32 -> fp8 e4m3, MFMA-fragment-tiled, in d_ws (48 KB).
//   main:   grid B/64, block 256 (4 waves), LDS 64 KB -> 2 blocks/CU.
//           Per wave: 16 KB private LDS scratch; issue 8 act + 8 ema
//           global_load_lds (16B width, coalesced, zero VGPR cost) in one
//           burst -> vmcnt(8) -> consume act -> vmcnt(0) -> consume ema.
//           Within-row source permutation g=(p&24)|((p&7)^(row&7)) makes the
//           strided (row,seg) b128 readback XOR-bank-clean (both-sides rule).
//           A packed fp8 with gs=(2/ln2)*inva -> MFMA acc = (2/ln2)*dot.
//           Fully-unrolled 24-tile fp8 MFMA loop, B from L2-resident qt.
//           S2 kept as per-class sums (compile-time tile class; boundary
//           tiles 7/15 predicated) -> mask/plab loads move to the epilogue.
//   finish: deterministic reduce of 2048 block partials.
//
//   S1 = sum exp2(acc) (9 zero pad rows -> -9);  def2 = (2/ln2)*f_hat.ef_hat
//   per = ln2*log2(exp2(def2)+S1-9) - ln2*(S2[label]+def2)/126
//   out = sum(mask*per)/B

#define D       128
#define NQ      375
#define QS      125
#define NT      24
#define INV126  (1.0f/126.0f)
#define LN2     0.6931471805599453f
#define INVLN2  1.4426950408889634f
#define WLDS    16384         // per-wave staging bytes (act 8K | ema 8K)
#define QT_BYTES 49152

typedef __attribute__((ext_vector_type(4))) float f32x4;

#if defined(__has_builtin)
#if __has_builtin(__builtin_amdgcn_cvt_pk_fp8_f32)
#define HAVE_CVT_FP8 1
#endif
#endif

#ifndef HAVE_CVT_FP8
static __device__ __forceinline__ unsigned f2e4m3_sw(float x) {
    unsigned u = __float_as_uint(x);
    unsigned s = (u >> 24) & 0x80;
    int e = (int)((u >> 23) & 0xFF);
    unsigned m = u & 0x7FFFFF;
    if (e == 0) return s;
    int te = e - 120;
    unsigned val;
    if (te >= 1) {
        unsigned keep = m >> 20;
        unsigned rest = m & 0xFFFFF;
        keep += (rest > 0x80000) || (rest == 0x80000 && (keep & 1));
        if (keep == 8) { keep = 0; te += 1; }
        val = (te >= 16) ? 0x7E : ((unsigned)(te << 3) | keep);
    } else {
        unsigned full = m | 0x800000;
        int sh = 21 - te;
        if (sh > 31) val = 0;
        else {
            unsigned keep = full >> sh;
            unsigned rem = full & ((1u << sh) - 1);
            unsigned half = 1u << (sh - 1);
            keep += (rem > half) || (rem == half && (keep & 1));
            val = keep;
        }
    }
    return s | val;
}
#endif

static __device__ __forceinline__ unsigned pk4(float4 v) {
#ifdef HAVE_CVT_FP8
    int r = __builtin_amdgcn_cvt_pk_fp8_f32(v.x, v.y, 0, false);
    r = __builtin_amdgcn_cvt_pk_fp8_f32(v.z, v.w, r, true);
    return (unsigned)r;
#else
    return f2e4m3_sw(v.x) | (f2e4m3_sw(v.y) << 8)
         | (f2e4m3_sw(v.z) << 16) | (f2e4m3_sw(v.w) << 24);
#endif
}

static __device__ __forceinline__ long pk8(float gs, float4 a, float4 b) {
    float4 sa = make_float4(gs * a.x, gs * a.y, gs * a.z, gs * a.w);
    float4 sb = make_float4(gs * b.x, gs * b.y, gs * b.z, gs * b.w);
    unsigned lo = pk4(sa), hi = pk4(sb);
    return (long)(((unsigned long)hi << 32) | (unsigned long)lo);
}

static __device__ __forceinline__ void glds16(const void* g, void* l) {
    __builtin_amdgcn_global_load_lds(
        (const __attribute__((address_space(1))) void*)g,
        (__attribute__((address_space(3))) void*)l, 16, 0, 0);
}

#define WAITV(n) do { asm volatile("s_waitcnt vmcnt(" #n ")" ::: "memory"); \
                      __builtin_amdgcn_sched_barrier(0); } while (0)

// ---- prep: queue -> fp8, fragment-tiled ----
__global__ void pgc_prep(const float* __restrict__ queue,
                         unsigned long long* __restrict__ qt)
{
    int u = blockIdx.x * 256 + threadIdx.x;      // 0..6143
    if (u >= 6144) return;
    int l = u & 63, ks = (u >> 6) & 3, nt = u >> 8;
    int row = nt * 16 + (l & 15);
    int k0 = (l >> 4) * 32 + ks * 8;
    float4 a = make_float4(0.f, 0.f, 0.f, 0.f);
    float4 b = make_float4(0.f, 0.f, 0.f, 0.f);
    if (row < NQ) {
        const float* p = queue + row * D + k0;
        a = *(const float4*)p;
        b = *(const float4*)(p + 4);
    }
    unsigned lo = pk4(a), hi = pk4(b);
    qt[u] = ((unsigned long long)hi << 32) | (unsigned long long)lo;
}

// ---- main ----
__global__ __launch_bounds__(256, 2) void pgc_main(
    const float* __restrict__ act,
    const float* __restrict__ ema,
    const float* __restrict__ plab,
    const float* __restrict__ mask,
    const unsigned long long* __restrict__ qt,
    float* __restrict__ partial,
    int B)
{
    __shared__ unsigned char stage[4 * WLDS];    // 64 KB
    __shared__ float s_red[4];

    const int tid = threadIdx.x;
    const int w   = tid >> 6;
    const int l   = tid & 63;
    const int lr  = l & 15;        // own sample row / C col
    const int seg = l >> 4;        // k-segment / C row group
    const int wavebase = w * WLDS;
    const long rowbase = (long)blockIdx.x * 64 + w * 16;

    // ---- burst-issue 16 KB of glds (act 8, ema 8); zero VGPR cost ----
    {
        const int p = l & 31;
        const int hpar = l >> 5;
        #pragma unroll
        for (int i = 0; i < 8; ++i) {
            int rr = 2 * i + hpar;
            long grow = rowbase + rr; if (grow >= (long)B) grow = (long)B - 1;
            int g = (p & 24) | ((p & 7) ^ (rr & 7));    // inverse swizzle (coalesced)
            glds16(act + grow * D + g * 4, &stage[wavebase + i * 1024]);
        }
        #pragma unroll
        for (int i = 0; i < 8; ++i) {
            int rr = 2 * i + hpar;
            long grow = rowbase + rr; if (grow >= (long)B) grow = (long)B - 1;
            int g = (p & 24) | ((p & 7) ^ (rr & 7));
            glds16(ema + grow * D + g * 4, &stage[wavebase + 8192 + i * 1024]);
        }
    }

    // ---- act ready (8 ema still in flight) ----
    WAITV(8);
    float4 f4[8];
    #pragma unroll
    for (int j = 0; j < 8; ++j) {
        int p = (seg * 8) | (j ^ (lr & 7));             // read-side swizzle
        f4[j] = *(const float4*)&stage[wavebase + lr * 512 + p * 16];
    }
    float ssa = 0.f;
    #pragma unroll
    for (int j = 0; j < 8; ++j)
        ssa += f4[j].x*f4[j].x + f4[j].y*f4[j].y + f4[j].z*f4[j].z + f4[j].w*f4[j].w;
    ssa += __shfl_xor(ssa, 16); ssa += __shfl_xor(ssa, 32);
    const float inva = 1.0f / fmaxf(sqrtf(ssa), 1e-12f);
    const float gs   = 2.0f * INVLN2 * inva;            // fold 2/ln2 + norm into A

    long af[4];
    #pragma unroll
    for (int ks = 0; ks < 4; ++ks)                      // k = seg*32 + ks*8 ..
        af[ks] = pk8(gs, f4[2 * ks], f4[2 * ks + 1]);

    // ---- ema ready ----
    WAITV(0);
    float sse = 0.f, dae = 0.f;
    #pragma unroll
    for (int j = 0; j < 8; ++j) {
        int p = (seg * 8) | (j ^ (lr & 7));
        float4 e = *(const float4*)&stage[wavebase + 8192 + lr * 512 + p * 16];
        sse += e.x*e.x + e.y*e.y + e.z*e.z + e.w*e.w;
        dae += f4[j].x*e.x + f4[j].y*e.y + f4[j].z*e.z + f4[j].w*e.w;
    }
    sse += __shfl_xor(sse, 16); sse += __shfl_xor(sse, 32);
    dae += __shfl_xor(dae, 16); dae += __shfl_xor(dae, 32);
    const float inve = 1.0f / fmaxf(sqrtf(sse), 1e-12f);
    const float def2 = 2.0f * INVLN2 * dae * inva * inve;   // base-2 domain

    // ---- fully-unrolled 24-tile fp8 MFMA loop; per-class S2 ----
    float S1[4]  = {0.f, 0.f, 0.f, 0.f};
    float S20[4] = {0.f, 0.f, 0.f, 0.f};
    float S21[4] = {0.f, 0.f, 0.f, 0.f};
    float S22[4] = {0.f, 0.f, 0.f, 0.f};

    #pragma unroll
    for (int nt = 0; nt < NT; ++nt) {
        long b[4];
        #pragma unroll
        for (int ks = 0; ks < 4; ++ks)
            b[ks] = (long)qt[nt * 256 + ks * 64 + l];   // coalesced b64 (L2)
        f32x4 acc = {0.f, 0.f, 0.f, 0.f};
        acc = __builtin_amdgcn_mfma_f32_16x16x32_fp8_fp8(af[0], b[0], acc, 0, 0, 0);
        acc = __builtin_amdgcn_mfma_f32_16x16x32_fp8_fp8(af[1], b[1], acc, 0, 0, 0);
        acc = __builtin_amdgcn_mfma_f32_16x16x32_fp8_fp8(af[2], b[2], acc, 0, 0, 0);
        acc = __builtin_amdgcn_mfma_f32_16x16x32_fp8_fp8(af[3], b[3], acc, 0, 0, 0);
        const int col = nt * 16 + lr;
        #pragma unroll
        for (int r = 0; r < 4; ++r) {
            S1[r] += exp2f(acc[r]);
            if      (nt <= 6)  S20[r] += acc[r];
            else if (nt == 7)  { if (col < 125) S20[r] += acc[r]; else S21[r] += acc[r]; }
            else if (nt <= 14) S21[r] += acc[r];
            else if (nt == 15) { if (col < 250) S21[r] += acc[r]; else S22[r] += acc[r]; }
            else               S22[r] += acc[r];        // pad rows add 0
        }
    }

    // ---- epilogue: own-row scalars (loads moved here, after the hot loop) ----
    long grow_own = rowbase + lr;
    const bool valid = grow_own < (long)B;
    const long gr = valid ? grow_own : (long)B - 1;
    float mk = valid ? mask[gr] : 0.f;
    const float* pp = plab + gr * 3;
    float p0 = pp[0], p1 = pp[1], p2 = pp[2];
    int lb = 0; float bst = p0;
    if (p1 > bst) { bst = p1; lb = 1; }                 // first-max = argmax
    if (p2 > bst) { lb = 2; }

    // select S2 by label of output row m = seg*4+r, then reduce
    float S2s[4];
    #pragma unroll
    for (int r = 0; r < 4; ++r) {
        int lbm = __shfl(lb, seg * 4 + r);
        S2s[r] = (lbm == 0) ? S20[r] : ((lbm == 1) ? S21[r] : S22[r]);
    }
    #pragma unroll
    for (int r = 0; r < 4; ++r) {
        S1[r]  += __shfl_xor(S1[r], 1);
        S1[r]  += __shfl_xor(S1[r], 2);
        S1[r]  += __shfl_xor(S1[r], 4);
        S1[r]  += __shfl_xor(S1[r], 8);
        S2s[r] += __shfl_xor(S2s[r], 1);
        S2s[r] += __shfl_xor(S2s[r], 2);
        S2s[r] += __shfl_xor(S2s[r], 4);
        S2s[r] += __shfl_xor(S2s[r], 8);
    }

    float c = 0.f;
    #pragma unroll
    for (int r = 0; r < 4; ++r) {
        const int m = seg * 4 + r;
        const float d2 = __shfl(def2, m);
        const float mm = __shfl(mk, m);
        const float denom = exp2f(d2) + S1[r] - 9.0f;   // drop 9 pad rows
        const float per = LN2 * log2f(denom) - LN2 * (S2s[r] + d2) * INV126;
        if (lr == 0) c += mm * per;
    }
    c += __shfl_xor(c, 16);
    c += __shfl_xor(c, 32);
    if (l == 0) s_red[w] = c;
    __syncthreads();
    if (tid == 0)
        partial[blockIdx.x] = s_red[0] + s_red[1] + s_red[2] + s_red[3];
}

// ---- finish: deterministic tree reduce ----
__global__ void pgc_finish(const float* __restrict__ partial,
                           float* __restrict__ out, int n, float invB)
{
    __shared__ float r[4];
    const int tid = threadIdx.x;
    float s = 0.f;
    for (int i = tid; i < n; i += 256) s += partial[i];
    s += __shfl_xor(s, 1);  s += __shfl_xor(s, 2);
    s += __shfl_xor(s, 4);  s += __shfl_xor(s, 8);
    s += __shfl_xor(s, 16); s += __shfl_xor(s, 32);
    if ((tid & 63) == 0) r[tid >> 6] = s;
    __syncthreads();
    if (tid == 0) out[0] = (r[0] + r[1] + r[2] + r[3]) * invB;
}

extern "C" void kernel_launch(void* const* d_in, const int* in_sizes, int n_in,
                              void* d_out, int out_size, void* d_ws, size_t ws_size,
                              hipStream_t stream)
{
    const float* act   = (const float*)d_in[0];
    const float* ema   = (const float*)d_in[1];
    const float* plab  = (const float*)d_in[2];
    const float* mask  = (const float*)d_in[3];
    const float* queue = (const float*)d_in[4];
    float* out = (float*)d_out;

    const int B = in_sizes[0] / D;

    unsigned long long* qt = (unsigned long long*)d_ws;
    float* partial = (float*)((char*)d_ws + QT_BYTES);

    pgc_prep<<<24, 256, 0, stream>>>(queue, qt);

    const int grid = (B + 63) / 64;          // 2048 for B=131072
    pgc_main<<<grid, 256, 0, stream>>>(act, ema, plab, mask, qt, partial, B);

    pgc_finish<<<1, 256, 0, stream>>>(partial, out, grid, 1.0f / (float)B);
}

// Round 14
// 55.365 us; speedup vs baseline: 1.0853x; 1.0853x over previous
//
#include <hip/hip_runtime.h>
#include <math.h>

// PseudoGroupContrast — high-occupancy glds streaming + Qsum-in-MFMA.
//
//   prep:   queue fp32 -> fp8 e4m3, MFMA-fragment-tiled, in d_ws (48 KB).
//   prepQ:  per-class queue sums -> fp8 into pad rows 375..377 of the tiled
//           queue (tile 23, lr=7..9). Rows 378..383 stay zero and are skipped.
//   main:   grid B/64, block 256 (4 waves), LDS 32 KB -> 4 blocks/CU
//           (4 waves/SIMD). Per wave: 8 KB staging buffer used twice:
//           glds act(8x1KB) -> vmcnt0 -> ds_read -> lgkm0 -> glds ema(8)
//           (overlaps with act norm/fp8-pack) -> vmcnt0 -> ds_read ema.
//           A = fp8(2*inva*act) -> MFMA acc = 2*dot (base-e domain).
//           24-tile fp8 MFMA loop, B from L2-resident qt:
//             tiles 0..22: S1[r] += __expf(acc[r])      (375 real cols)
//             tile 23:     lr<7 -> S1; lane lr=7+c holds S2 for class c
//           S2sel = one variable-lane shuffle from tile-23 acc.
//           per = log(exp(def2)+S1) - (S2+def2)/126, def2 = 2*f_hat.ef_hat
//   finish: deterministic reduce of 2048 block partials -> out.

#define D       128
#define NQ      375
#define QS      125
#define INV126  (1.0f/126.0f)
#define WLDS    8192          // per-wave staging bytes (act, then ema)
#define QT_BYTES 49152

typedef __attribute__((ext_vector_type(4))) float f32x4;

#if defined(__has_builtin)
#if __has_builtin(__builtin_amdgcn_cvt_pk_fp8_f32)
#define HAVE_CVT_FP8 1
#endif
#endif

#ifndef HAVE_CVT_FP8
static __device__ __forceinline__ unsigned f2e4m3_sw(float x) {
    unsigned u = __float_as_uint(x);
    unsigned s = (u >> 24) & 0x80;
    int e = (int)((u >> 23) & 0xFF);
    unsigned m = u & 0x7FFFFF;
    if (e == 0) return s;
    int te = e - 120;
    unsigned val;
    if (te >= 1) {
        unsigned keep = m >> 20;
        unsigned rest = m & 0xFFFFF;
        keep += (rest > 0x80000) || (rest == 0x80000 && (keep & 1));
        if (keep == 8) { keep = 0; te += 1; }
        val = (te >= 16) ? 0x7E : ((unsigned)(te << 3) | keep);
    } else {
        unsigned full = m | 0x800000;
        int sh = 21 - te;
        if (sh > 31) val = 0;
        else {
            unsigned keep = full >> sh;
            unsigned rem = full & ((1u << sh) - 1);
            unsigned half = 1u << (sh - 1);
            keep += (rem > half) || (rem == half && (keep & 1));
            val = keep;
        }
    }
    return s | val;
}
#endif

static __device__ __forceinline__ unsigned pk4(float4 v) {
#ifdef HAVE_CVT_FP8
    int r = __builtin_amdgcn_cvt_pk_fp8_f32(v.x, v.y, 0, false);
    r = __builtin_amdgcn_cvt_pk_fp8_f32(v.z, v.w, r, true);
    return (unsigned)r;
#else
    return f2e4m3_sw(v.x) | (f2e4m3_sw(v.y) << 8)
         | (f2e4m3_sw(v.z) << 16) | (f2e4m3_sw(v.w) << 24);
#endif
}

static __device__ __forceinline__ unsigned char pk1(float x) {
#ifdef HAVE_CVT_FP8
    return (unsigned char)(__builtin_amdgcn_cvt_pk_fp8_f32(x, x, 0, false) & 0xff);
#else
    return (unsigned char)f2e4m3_sw(x);
#endif
}

static __device__ __forceinline__ long pk8(float gs, float4 a, float4 b) {
    float4 sa = make_float4(gs * a.x, gs * a.y, gs * a.z, gs * a.w);
    float4 sb = make_float4(gs * b.x, gs * b.y, gs * b.z, gs * b.w);
    unsigned lo = pk4(sa), hi = pk4(sb);
    return (long)(((unsigned long)hi << 32) | (unsigned long)lo);
}

static __device__ __forceinline__ void glds16(const void* g, void* l) {
    __builtin_amdgcn_global_load_lds(
        (const __attribute__((address_space(1))) void*)g,
        (__attribute__((address_space(3))) void*)l, 16, 0, 0);
}

#define WAITV(n) do { asm volatile("s_waitcnt vmcnt(" #n ")" ::: "memory"); \
                      __builtin_amdgcn_sched_barrier(0); } while (0)
#define WAITL()  do { asm volatile("s_waitcnt lgkmcnt(0)" ::: "memory"); \
                      __builtin_amdgcn_sched_barrier(0); } while (0)

// ---- prep: queue -> fp8, fragment-tiled (rows >= 375 zeroed) ----
__global__ void pgc_prep(const float* __restrict__ queue,
                         unsigned long long* __restrict__ qt)
{
    int u = blockIdx.x * 256 + threadIdx.x;      // 0..6143
    if (u >= 6144) return;
    int l = u & 63, ks = (u >> 6) & 3, nt = u >> 8;
    int row = nt * 16 + (l & 15);
    int k0 = (l >> 4) * 32 + ks * 8;
    float4 a = make_float4(0.f, 0.f, 0.f, 0.f);
    float4 b = make_float4(0.f, 0.f, 0.f, 0.f);
    if (row < NQ) {
        const float* p = queue + row * D + k0;
        a = *(const float4*)p;
        b = *(const float4*)(p + 4);
    }
    unsigned lo = pk4(a), hi = pk4(b);
    qt[u] = ((unsigned long long)hi << 32) | (unsigned long long)lo;
}

// ---- prepQ: class sums into pad rows 375..377 (runs after pgc_prep) ----
__global__ void pgc_prep_qsum(const float* __restrict__ queue,
                              unsigned char* __restrict__ qtb)
{
    int c = blockIdx.x;          // 0..2
    int d = threadIdx.x;         // 0..127
    float s = 0.f;
    const float* p = queue + (long)c * QS * D + d;
    for (int r = 0; r < QS; ++r) s += p[r * D];
    int seg = d >> 5, ks = (d >> 3) & 3, j = d & 7;
    int u = 23 * 256 + ks * 64 + seg * 16 + 7 + c;   // tile 23, lr = 7+c
    qtb[u * 8 + j] = pk1(s);
}

// ---- main ----
__global__ __launch_bounds__(256, 4) void pgc_main(
    const float* __restrict__ act,
    const float* __restrict__ ema,
    const float* __restrict__ plab,
    const float* __restrict__ mask,
    const unsigned long long* __restrict__ qt,
    float* __restrict__ partial,
    int B)
{
    __shared__ unsigned char stage[4 * WLDS];    // 32 KB
    __shared__ float s_red[4];

    const int tid = threadIdx.x;
    const int w   = tid >> 6;
    const int l   = tid & 63;
    const int lr  = l & 15;        // own sample row / C col
    const int seg = l >> 4;        // k-segment / C row group
    const int wavebase = w * WLDS;
    const long rowbase = (long)blockIdx.x * 64 + w * 16;

    const int p    = l & 31;
    const int hpar = l >> 5;

    // ---- stage act: 8x glds (16 rows x 512 B), swizzled source ----
    #pragma unroll
    for (int i = 0; i < 8; ++i) {
        int rr = 2 * i + hpar;
        long grow = rowbase + rr; if (grow >= (long)B) grow = (long)B - 1;
        int g = (p & 24) | ((p & 7) ^ (rr & 7));
        glds16(act + grow * D + g * 4, &stage[wavebase + i * 1024]);
    }
    WAITV(0);
    float4 f4[8];
    #pragma unroll
    for (int j = 0; j < 8; ++j) {
        int ph = (seg * 8) | (j ^ (lr & 7));         // read-side swizzle
        f4[j] = *(const float4*)&stage[wavebase + lr * 512 + ph * 16];
    }
    WAITL();   // act reads landed in regs -> safe to overwrite buffer

    // ---- stage ema into the SAME buffer (flight hidden under act compute) ----
    #pragma unroll
    for (int i = 0; i < 8; ++i) {
        int rr = 2 * i + hpar;
        long grow = rowbase + rr; if (grow >= (long)B) grow = (long)B - 1;
        int g = (p & 24) | ((p & 7) ^ (rr & 7));
        glds16(ema + grow * D + g * 4, &stage[wavebase + i * 1024]);
    }

    // ---- act norms + fp8 pack (overlaps ema flight) ----
    float ssa = 0.f;
    #pragma unroll
    for (int j = 0; j < 8; ++j)
        ssa += f4[j].x*f4[j].x + f4[j].y*f4[j].y + f4[j].z*f4[j].z + f4[j].w*f4[j].w;
    ssa += __shfl_xor(ssa, 16); ssa += __shfl_xor(ssa, 32);
    const float inva = 1.0f / fmaxf(sqrtf(ssa), 1e-12f);
    const float gs   = 2.0f * inva;                  // fold 1/T + norm into A

    long af[4];
    #pragma unroll
    for (int ks = 0; ks < 4; ++ks)                   // k = seg*32 + ks*8 ..
        af[ks] = pk8(gs, f4[2 * ks], f4[2 * ks + 1]);

    // ---- ema ready ----
    WAITV(0);
    float sse = 0.f, dae = 0.f;
    #pragma unroll
    for (int j = 0; j < 8; ++j) {
        int ph = (seg * 8) | (j ^ (lr & 7));
        float4 e = *(const float4*)&stage[wavebase + lr * 512 + ph * 16];
        sse += e.x*e.x + e.y*e.y + e.z*e.z + e.w*e.w;
        dae += f4[j].x*e.x + f4[j].y*e.y + f4[j].z*e.z + f4[j].w*e.w;
    }
    sse += __shfl_xor(sse, 16); sse += __shfl_xor(sse, 32);
    dae += __shfl_xor(dae, 16); dae += __shfl_xor(dae, 32);
    const float inve = 1.0f / fmaxf(sqrtf(sse), 1e-12f);
    const float def2 = 2.0f * dae * inva * inve;

    // ---- 24-tile fp8 MFMA loop; B from L2-resident qt ----
    float S1[4] = {0.f, 0.f, 0.f, 0.f};

    #pragma unroll
    for (int nt = 0; nt < 23; ++nt) {
        long b0 = (long)qt[nt * 256 +       l];
        long b1 = (long)qt[nt * 256 +  64 + l];
        long b2 = (long)qt[nt * 256 + 128 + l];
        long b3 = (long)qt[nt * 256 + 192 + l];
        f32x4 acc = {0.f, 0.f, 0.f, 0.f};
        acc = __builtin_amdgcn_mfma_f32_16x16x32_fp8_fp8(af[0], b0, acc, 0, 0, 0);
        acc = __builtin_amdgcn_mfma_f32_16x16x32_fp8_fp8(af[1], b1, acc, 0, 0, 0);
        acc = __builtin_amdgcn_mfma_f32_16x16x32_fp8_fp8(af[2], b2, acc, 0, 0, 0);
        acc = __builtin_amdgcn_mfma_f32_16x16x32_fp8_fp8(af[3], b3, acc, 0, 0, 0);
        #pragma unroll
        for (int r = 0; r < 4; ++r)
            S1[r] += __expf(acc[r]);
    }

    // tile 23: cols 368..374 real (lr<7); lr=7..9 hold S2 per class; 10..15 zero
    f32x4 a23 = {0.f, 0.f, 0.f, 0.f};
    {
        long b0 = (long)qt[23 * 256 +       l];
        long b1 = (long)qt[23 * 256 +  64 + l];
        long b2 = (long)qt[23 * 256 + 128 + l];
        long b3 = (long)qt[23 * 256 + 192 + l];
        a23 = __builtin_amdgcn_mfma_f32_16x16x32_fp8_fp8(af[0], b0, a23, 0, 0, 0);
        a23 = __builtin_amdgcn_mfma_f32_16x16x32_fp8_fp8(af[1], b1, a23, 0, 0, 0);
        a23 = __builtin_amdgcn_mfma_f32_16x16x32_fp8_fp8(af[2], b2, a23, 0, 0, 0);
        a23 = __builtin_amdgcn_mfma_f32_16x16x32_fp8_fp8(af[3], b3, a23, 0, 0, 0);
        if (lr < 7) {
            #pragma unroll
            for (int r = 0; r < 4; ++r)
                S1[r] += __expf(a23[r]);
        }
    }

    // ---- own-row scalars (after the hot loop) ----
    long grow_own = rowbase + lr;
    const bool valid = grow_own < (long)B;
    const long gr = valid ? grow_own : (long)B - 1;
    float mk = valid ? mask[gr] : 0.f;
    const float* pp = plab + gr * 3;
    float p0 = pp[0], p1 = pp[1], p2 = pp[2];
    int lb = 0; float bst = p0;
    if (p1 > bst) { bst = p1; lb = 1; }              // first-max = argmax
    if (p2 > bst) { lb = 2; }

    // ---- reduce S1 over the 16 column lanes ----
    #pragma unroll
    for (int r = 0; r < 4; ++r) {
        S1[r] += __shfl_xor(S1[r], 1);
        S1[r] += __shfl_xor(S1[r], 2);
        S1[r] += __shfl_xor(S1[r], 4);
        S1[r] += __shfl_xor(S1[r], 8);
    }

    // ---- epilogue: S2 via one variable-lane shuffle from tile-23 acc ----
    float c = 0.f;
    #pragma unroll
    for (int r = 0; r < 4; ++r) {
        const int m   = seg * 4 + r;                 // output row of this lane grp
        const int lbm = __shfl(lb, m);               // label of row m
        const float S2 = __shfl(a23[r], (l & 48) + 7 + lbm);  // C[m][375+lbm]
        const float d2 = __shfl(def2, m);
        const float mm = __shfl(mk, m);
        const float denom = __expf(d2) + S1[r];      // exactly 375 real cols
        const float per = __logf(denom) - (S2 + d2) * INV126;
        if (lr == 0) c += mm * per;
    }
    c += __shfl_xor(c, 16);
    c += __shfl_xor(c, 32);
    if (l == 0) s_red[w] = c;
    __syncthreads();
    if (tid == 0)
        partial[blockIdx.x] = s_red[0] + s_red[1] + s_red[2] + s_red[3];
}

// ---- finish: deterministic tree reduce ----
__global__ void pgc_finish(const float* __restrict__ partial,
                           float* __restrict__ out, int n, float invB)
{
    __shared__ float r[4];
    const int tid = threadIdx.x;
    float s = 0.f;
    for (int i = tid; i < n; i += 256) s += partial[i];
    s += __shfl_xor(s, 1);  s += __shfl_xor(s, 2);
    s += __shfl_xor(s, 4);  s += __shfl_xor(s, 8);
    s += __shfl_xor(s, 16); s += __shfl_xor(s, 32);
    if ((tid & 63) == 0) r[tid >> 6] = s;
    __syncthreads();
    if (tid == 0) out[0] = (r[0] + r[1] + r[2] + r[3]) * invB;
}

extern "C" void kernel_launch(void* const* d_in, const int* in_sizes, int n_in,
                              void* d_out, int out_size, void* d_ws, size_t ws_size,
                              hipStream_t stream)
{
    const float* act   = (const float*)d_in[0];
    const float* ema   = (const float*)d_in[1];
    const float* plab  = (const float*)d_in[2];
    const float* mask  = (const float*)d_in[3];
    const float* queue = (const float*)d_in[4];
    float* out = (float*)d_out;

    const int B = in_sizes[0] / D;

    unsigned long long* qt = (unsigned long long*)d_ws;
    float* partial = (float*)((char*)d_ws + QT_BYTES);

    pgc_prep<<<24, 256, 0, stream>>>(queue, qt);
    pgc_prep_qsum<<<3, 128, 0, stream>>>(queue, (unsigned char*)d_ws);

    const int grid = (B + 63) / 64;          // 2048 for B=131072
    pgc_main<<<grid, 256, 0, stream>>>(act, ema, plab, mask, qt, partial, B);

    pgc_finish<<<1, 256, 0, stream>>>(partial, out, grid, 1.0f / (float)B);
}